// Round 7
// baseline (308.153 us; speedup 1.0000x reference)
//
#include <hip/hip_runtime.h>

#define NEG (-1e30f)

constexpr int Bn = 16;
constexpr int Tn = 512;
constexpr int Dn = 256;
constexpr int Vn = 4233;
constexpr int Vp = 4352;   // V padded to 34*128
constexpr int Ln = 64;     // LMAX
constexpr int Un = 80;     // padded gathered-label count (65 -> 80 = 5*16)
constexpr int LP = 72;     // LDS row stride in bf16 for gemm_gather (64 + 8 pad)
constexpr int NCB = 34;    // number of 128-wide column blocks in gemm_se
constexpr int Mtot = Bn * Tn;  // 8192

#define INV_LN2 1.4426950408889634f
#define LN2     0.6931471805599453f

typedef __attribute__((ext_vector_type(8))) short short8;
typedef __attribute__((ext_vector_type(4))) float f32x4;

// native base-2 transcendentals (v_exp_f32 / v_log_f32)
__device__ __forceinline__ float ex2(float x) { return __builtin_amdgcn_exp2f(x); }
__device__ __forceinline__ float lg2(float x) { return __builtin_amdgcn_logf(x); }

__device__ __forceinline__ unsigned short cvt_bf16(float f) {
    unsigned int u = __float_as_uint(f);
    u = (u + 0x7fffu + ((u >> 16) & 1u)) >> 16;
    return (unsigned short)u;
}

// async global->LDS, 16B per lane; LDS dest is wave-uniform base + lane*16
__device__ __forceinline__ void gl_lds16(const void* g, void* l) {
    __builtin_amdgcn_global_load_lds(
        (const __attribute__((address_space(1))) void*)g,
        (__attribute__((address_space(3))) void*)l,
        16, 0, 0);
}

// value from lane-1 (wave_shr:1); lane 0 takes `edge`
__device__ __forceinline__ float dpp_shr1(float v, float edge) {
    return __int_as_float(__builtin_amdgcn_update_dpp(
        __float_as_int(edge), __float_as_int(v), 0x138, 0xF, 0xF, false));
}

// ---------------- conversion / gather prep ----------------
__global__ __launch_bounds__(256) void conv(
    const float* __restrict__ hs, const float* __restrict__ W,
    const float* __restrict__ bias, const int* __restrict__ ys,
    unsigned short* __restrict__ hs_b, unsigned short* __restrict__ w_b,
    unsigned short* __restrict__ wg_b, float* __restrict__ gbias)
{
    const int gid = blockIdx.x * 256 + threadIdx.x;
    const int stride = gridDim.x * 256;
    const float4* hs4 = (const float4*)hs;
    const float4* W4  = (const float4*)W;

    for (int i = gid; i < (Bn * Tn * Dn) / 4; i += stride) {
        float4 v = hs4[i];
        ushort4 o = make_ushort4(cvt_bf16(v.x), cvt_bf16(v.y), cvt_bf16(v.z), cvt_bf16(v.w));
        *(ushort4*)(&hs_b[i * 4]) = o;
    }
    for (int i = gid; i < Vp * (Dn / 4); i += stride) {
        int row = i >> 6;
        float4 v = make_float4(0.f, 0.f, 0.f, 0.f);
        if (row < Vn) v = W4[i];
        ushort4 o = make_ushort4(cvt_bf16(v.x), cvt_bf16(v.y), cvt_bf16(v.z), cvt_bf16(v.w));
        *(ushort4*)(&w_b[i * 4]) = o;
    }
    for (int i = gid; i < Bn * Un * (Dn / 4); i += stride) {
        int b = i / (Un * (Dn / 4));
        int rem = i - b * (Un * (Dn / 4));
        int u = rem >> 6;
        int k4 = rem & 63;
        int v = (u == 0) ? 0 : ((u <= Ln) ? ys[b * Ln + u - 1] : -1);
        float4 val = make_float4(0.f, 0.f, 0.f, 0.f);
        if (v >= 0) val = W4[(size_t)v * (Dn / 4) + k4];
        ushort4 o = make_ushort4(cvt_bf16(val.x), cvt_bf16(val.y), cvt_bf16(val.z), cvt_bf16(val.w));
        *(ushort4*)(&wg_b[i * 4]) = o;
    }
    for (int i = gid; i < Bn * Un; i += stride) {
        int b = i / Un;
        int u = i - b * Un;
        int v = (u == 0) ? 0 : ((u <= Ln) ? ys[b * Ln + u - 1] : -1);
        gbias[i] = (v >= 0) ? bias[v] : 0.0f;
    }
}

// ---------------- main GEMM: partial sums of exp over V ----------------
__global__ __launch_bounds__(256) void gemm_se(
    const unsigned short* __restrict__ hs_b, const unsigned short* __restrict__ w_b,
    const float* __restrict__ bias, float* __restrict__ sep)
{
    __shared__ __align__(16) short lsA[128 * 64];
    __shared__ __align__(16) short lsB[128 * 64];

    const int tid = threadIdx.x;
    const int lane = tid & 63;
    const int w = tid >> 6;
    const int lr = lane & 15;
    const int kq = lane >> 4;
    const int m0 = blockIdx.x * 128;
    const int n0 = blockIdx.y * 128;
    const int mw = w * 32;

    const int srow = lane >> 3;
    const int scol = (lane & 7) * 8;

    f32x4 acc[2][8];
    #pragma unroll
    for (int mf = 0; mf < 2; ++mf)
        #pragma unroll
        for (int nf = 0; nf < 8; ++nf)
            acc[mf][nf] = (f32x4){0.f, 0.f, 0.f, 0.f};

    for (int ks = 0; ks < 4; ++ks) {
        const int k0 = ks * 64;
        __syncthreads();
        #pragma unroll
        for (int j = 0; j < 4; ++j) {
            int c = w * 4 + j;
            int row = c * 8 + srow;
            gl_lds16(hs_b + (size_t)(m0 + row) * Dn + k0 + scol, (char*)lsA + c * 1024);
            gl_lds16(w_b  + (size_t)(n0 + row) * Dn + k0 + scol, (char*)lsB + c * 1024);
        }
        __syncthreads();

        #pragma unroll
        for (int sub = 0; sub < 2; ++sub) {
            short8 af[2], bf[8];
            #pragma unroll
            for (int mf = 0; mf < 2; ++mf)
                af[mf] = *(const short8*)(&lsA[(mw + mf * 16 + lr) * 64 + sub * 32 + kq * 8]);
            #pragma unroll
            for (int nf = 0; nf < 8; ++nf)
                bf[nf] = *(const short8*)(&lsB[(nf * 16 + lr) * 64 + sub * 32 + kq * 8]);
            #pragma unroll
            for (int mf = 0; mf < 2; ++mf)
                #pragma unroll
                for (int nf = 0; nf < 8; ++nf)
                    acc[mf][nf] = __builtin_amdgcn_mfma_f32_16x16x32_bf16(
                        af[mf], bf[nf], acc[mf][nf], 0, 0, 0);
        }
    }

    float bcol[8]; bool valid[8];
    #pragma unroll
    for (int nf = 0; nf < 8; ++nf) {
        int col = n0 + nf * 16 + lr;
        valid[nf] = (col < Vn);
        bcol[nf] = valid[nf] ? bias[col] : 0.0f;
    }
    #pragma unroll
    for (int mf = 0; mf < 2; ++mf) {
        #pragma unroll
        for (int r = 0; r < 4; ++r) {
            float s = 0.0f;
            #pragma unroll
            for (int nf = 0; nf < 8; ++nf)
                if (valid[nf]) s += __expf(acc[mf][nf][r] + bcol[nf]);
            #pragma unroll
            for (int off = 1; off < 16; off <<= 1) s += __shfl_xor(s, off, 64);
            if (lr == 0)
                sep[(size_t)blockIdx.y * Mtot + m0 + mw + mf * 16 + kq * 4 + r] = s;
        }
    }
}

// ---------------- gathered-label GEMM -> normalized log2-probs ----------------
// glp[b][t][u] = (logit + bias - lse) * (1/ln2)   [log2 domain for ctc_fwd]
__global__ __launch_bounds__(256) void gemm_gather(
    const unsigned short* __restrict__ hs_b, const unsigned short* __restrict__ wg_b,
    const float* __restrict__ gbias, const float* __restrict__ sep,
    float* __restrict__ glp)
{
    __shared__ short lsA[128 * LP];
    __shared__ short lsB[Un * LP];
    __shared__ float red2[128][2];
    __shared__ float sh_lse[128];

    const int tid = threadIdx.x;
    const int lane = tid & 63;
    const int w = tid >> 6;
    const int lr = lane & 15;
    const int kq = lane >> 4;
    const int m0 = blockIdx.x * 128;
    const int b = blockIdx.y;
    const int mw = w * 32;

    f32x4 acc[2][5];
    #pragma unroll
    for (int mf = 0; mf < 2; ++mf)
        #pragma unroll
        for (int nf = 0; nf < 5; ++nf)
            acc[mf][nf] = (f32x4){0.f, 0.f, 0.f, 0.f};

    for (int ks = 0; ks < 4; ++ks) {
        const int k0 = ks * 64;
        float4 ga[4];
        #pragma unroll
        for (int j = 0; j < 4; ++j) {
            int ch = tid + 256 * j;
            int row = ch >> 3, off = (ch & 7) * 8;
            ga[j] = *(const float4*)(hs_b + (size_t)(b * Tn + m0 + row) * Dn + k0 + off);
        }
        float4 gbv[3];
        int nb = 0;
        for (int ch = tid; ch < Un * 8; ch += 256, ++nb) {
            int row = ch >> 3, off = (ch & 7) * 8;
            gbv[nb] = *(const float4*)(wg_b + (size_t)(b * Un + row) * Dn + k0 + off);
        }
        __syncthreads();
        #pragma unroll
        for (int j = 0; j < 4; ++j) {
            int ch = tid + 256 * j;
            int row = ch >> 3, off = (ch & 7) * 8;
            *(float4*)(&lsA[row * LP + off]) = ga[j];
        }
        nb = 0;
        for (int ch = tid; ch < Un * 8; ch += 256, ++nb) {
            int row = ch >> 3, off = (ch & 7) * 8;
            *(float4*)(&lsB[row * LP + off]) = gbv[nb];
        }
        __syncthreads();

        #pragma unroll
        for (int sub = 0; sub < 2; ++sub) {
            short8 af[2], bf[5];
            #pragma unroll
            for (int mf = 0; mf < 2; ++mf)
                af[mf] = *(const short8*)(&lsA[(mw + mf * 16 + lr) * LP + sub * 32 + kq * 8]);
            #pragma unroll
            for (int nf = 0; nf < 5; ++nf)
                bf[nf] = *(const short8*)(&lsB[(nf * 16 + lr) * LP + sub * 32 + kq * 8]);
            #pragma unroll
            for (int mf = 0; mf < 2; ++mf)
                #pragma unroll
                for (int nf = 0; nf < 5; ++nf)
                    acc[mf][nf] = __builtin_amdgcn_mfma_f32_16x16x32_bf16(
                        af[mf], bf[nf], acc[mf][nf], 0, 0, 0);
        }
    }

    {
        int r = tid >> 1, half = tid & 1;
        int g = b * Tn + m0 + r;
        float s = 0.0f;
        #pragma unroll
        for (int j = 0; j < 17; ++j) {
            int c = half * 17 + j;
            s += sep[(size_t)c * Mtot + g];
        }
        red2[r][half] = s;
    }
    __syncthreads();
    if (tid < 128) sh_lse[tid] = __logf(red2[tid][0] + red2[tid][1]);
    __syncthreads();

    #pragma unroll
    for (int mf = 0; mf < 2; ++mf) {
        #pragma unroll
        for (int r = 0; r < 4; ++r) {
            int lrow = mw + mf * 16 + kq * 4 + r;
            int t = m0 + lrow;
            float lse = sh_lse[lrow];
            #pragma unroll
            for (int nf = 0; nf < 5; ++nf) {
                int u = nf * 16 + lr;
                glp[((size_t)(b * Tn + t)) * Un + u] =
                    (acc[mf][nf][r] + gbias[b * Un + u] - lse) * INV_LN2;
            }
        }
    }
}

// ---------------- CTC forward recursion (log2 domain) ----------------
// 4 blocks x 4 waves; wave handles one batch element. Lane l holds
// aOdd=alpha[2l+1], aEven=alpha[2l+2]; alpha[0] tracked wave-redundantly.
// Cross-lane via DPP wave_shr:1 (VALU, no LDS). Loads prefetched P ahead.
__global__ __launch_bounds__(256) void ctc_fwd(
    const float* __restrict__ glp, const int* __restrict__ ys,
    const int* __restrict__ hlens, const int* __restrict__ ylens,
    float* __restrict__ ll_out)
{
    const int w = threadIdx.x >> 6;
    const int l = threadIdx.x & 63;
    const int b = blockIdx.x * 4 + w;

    const int hl = hlens[b];
    int yl  = ys[b * Ln + l];
    int ylm = (l >= 1) ? ys[b * Ln + l - 1] : -1;
    const bool allow1 = (l >= 1) && (yl != ylm);

    const float* gb = glp + (size_t)b * Tn * Un;

    // t=0 init (log2 domain)
    float A0    = gb[0];
    float aOdd  = (l == 0) ? gb[1] : NEG;
    float aEven = NEG;

    constexpr int P = 8;
    float lplR[P], lpbR[P];
    #pragma unroll
    for (int j = 0; j < P; ++j) {
        int t = 1 + j;
        lplR[j] = gb[t * Un + 1 + l];
        lpbR[j] = gb[t * Un];
    }

    for (int tc = 1; tc < Tn; tc += P) {
        #pragma unroll
        for (int j = 0; j < P; ++j) {
            int t = tc + j;
            if (t < Tn) {
                float lpl = lplR[j];
                float lpb = lpbR[j];
                int tp = t + P;
                if (tp < Tn) {
                    lplR[j] = gb[tp * Un + 1 + l];
                    lpbR[j] = gb[tp * Un];
                }

                float pOdd  = dpp_shr1(aOdd, NEG);   // alpha[2l-1]; lane0 -> NEG
                float pEven = dpp_shr1(aEven, A0);   // alpha[2l];   lane0 -> alpha[0]
                float pA = allow1 ? pOdd : NEG;

                // odd state s=2l+1
                float m1 = fmaxf(fmaxf(aOdd, pEven), pA);
                float s1 = ex2(aOdd - m1) + ex2(pEven - m1) + ex2(pA - m1);
                float uOdd = (m1 + lpl) + lg2(s1);

                // even state s=2l+2 (lane-local)
                float m2 = fmaxf(aEven, aOdd);
                float s2 = ex2(aEven - m2) + ex2(aOdd - m2);
                float uEven = (m2 + lpb) + lg2(s2);

                float uA0 = A0 + lpb;

                bool act = t < hl;
                aOdd  = act ? uOdd  : aOdd;
                aEven = act ? uEven : aEven;
                A0    = act ? uA0   : A0;
            }
        }
    }

    int L = ylens[b];
    if (l == L - 1) {
        // alpha[2L] = aEven, alpha[2L-1] = aOdd  (both on lane L-1)
        float m = fmaxf(aOdd, aEven);
        float ll2 = m + lg2(ex2(aOdd - m) + ex2(aEven - m));
        ll_out[b] = ll2 * LN2;
    }
}

__global__ void finalize(const float* __restrict__ ll, float* __restrict__ out) {
    if (threadIdx.x == 0 && blockIdx.x == 0) {
        float s = 0.0f;
        #pragma unroll
        for (int b = 0; b < Bn; ++b) s += ll[b];
        out[0] = -s / (float)Bn;
    }
}

extern "C" void kernel_launch(void* const* d_in, const int* in_sizes, int n_in,
                              void* d_out, int out_size, void* d_ws, size_t ws_size,
                              hipStream_t stream) {
    const float* hs    = (const float*)d_in[0];
    const int*   hlens = (const int*)d_in[1];
    const int*   ys    = (const int*)d_in[2];
    const int*   ylens = (const int*)d_in[3];
    const float* W     = (const float*)d_in[4];
    const float* bias  = (const float*)d_in[5];
    float* out = (float*)d_out;

    char* ws = (char*)d_ws;
    unsigned short* hs_b = (unsigned short*)(ws);                       // 4,194,304 B
    unsigned short* w_b  = (unsigned short*)(ws + 4194304);             // 2,228,224 B
    unsigned short* wg_b = (unsigned short*)(ws + 6422528);             //   655,360 B
    float* glp   = (float*)(ws + 7077888);                              // 2,621,440 B
    float* sep   = (float*)(ws + 9699328);                              // 1,114,112 B
    float* gbias = (float*)(ws + 10813440);                             //     5,120 B
    float* ll    = (float*)(ws + 10818560);                             //        64 B

    conv<<<1024, 256, 0, stream>>>(hs, W, bias, ys, hs_b, w_b, wg_b, gbias);
    gemm_se<<<dim3(64, NCB), 256, 0, stream>>>(hs_b, w_b, bias, sep);
    gemm_gather<<<dim3(4, 16), 256, 0, stream>>>(hs_b, wg_b, gbias, sep, glp);
    ctc_fwd<<<Bn / 4, 256, 0, stream>>>(glp, ys, hlens, ylens, ll);
    finalize<<<1, 64, 0, stream>>>(ll, out);
}

// Round 8
// 203.515 us; speedup vs baseline: 1.5142x; 1.5142x over previous
//
#include <hip/hip_runtime.h>

#define NEG (-1e30f)

constexpr int Bn = 16;
constexpr int Tn = 512;
constexpr int Dn = 256;
constexpr int Vn = 4233;
constexpr int Vp = 4352;   // V padded to 34*128
constexpr int Ln = 64;     // LMAX
constexpr int Un = 80;     // padded gathered-label count (65 -> 80 = 5*16)
constexpr int LP = 72;     // LDS row stride in bf16 for gemm_gather (64 + 8 pad)
constexpr int CS = 68;     // ctc LDS row stride in floats
constexpr int NCB = 34;    // number of 128-wide column blocks in gemm_se
constexpr int Mtot = Bn * Tn;  // 8192

#define INV_LN2 1.4426950408889634f
#define LN2     0.6931471805599453f

typedef __attribute__((ext_vector_type(8))) short short8;
typedef __attribute__((ext_vector_type(4))) float f32x4;

// native base-2 transcendentals (v_exp_f32 / v_log_f32)
__device__ __forceinline__ float ex2(float x) { return __builtin_amdgcn_exp2f(x); }
__device__ __forceinline__ float lg2(float x) { return __builtin_amdgcn_logf(x); }

__device__ __forceinline__ unsigned short cvt_bf16(float f) {
    unsigned int u = __float_as_uint(f);
    u = (u + 0x7fffu + ((u >> 16) & 1u)) >> 16;
    return (unsigned short)u;
}

// async global->LDS, 16B per lane; LDS dest is wave-uniform base + lane*16
__device__ __forceinline__ void gl_lds16(const void* g, void* l) {
    __builtin_amdgcn_global_load_lds(
        (const __attribute__((address_space(1))) void*)g,
        (__attribute__((address_space(3))) void*)l,
        16, 0, 0);
}

// value from lane-1 (wave_shr:1); lane 0 takes `edge`
__device__ __forceinline__ float dpp_shr1(float v, float edge) {
    return __int_as_float(__builtin_amdgcn_update_dpp(
        __float_as_int(edge), __float_as_int(v), 0x138, 0xF, 0xF, false));
}

// ---------------- conversion / gather prep ----------------
__global__ __launch_bounds__(256) void conv(
    const float* __restrict__ hs, const float* __restrict__ W,
    const float* __restrict__ bias, const int* __restrict__ ys,
    unsigned short* __restrict__ hs_b, unsigned short* __restrict__ w_b,
    unsigned short* __restrict__ wg_b, float* __restrict__ gbias)
{
    const int gid = blockIdx.x * 256 + threadIdx.x;
    const int stride = gridDim.x * 256;
    const float4* hs4 = (const float4*)hs;
    const float4* W4  = (const float4*)W;

    for (int i = gid; i < (Bn * Tn * Dn) / 4; i += stride) {
        float4 v = hs4[i];
        ushort4 o = make_ushort4(cvt_bf16(v.x), cvt_bf16(v.y), cvt_bf16(v.z), cvt_bf16(v.w));
        *(ushort4*)(&hs_b[i * 4]) = o;
    }
    for (int i = gid; i < Vp * (Dn / 4); i += stride) {
        int row = i >> 6;
        float4 v = make_float4(0.f, 0.f, 0.f, 0.f);
        if (row < Vn) v = W4[i];
        ushort4 o = make_ushort4(cvt_bf16(v.x), cvt_bf16(v.y), cvt_bf16(v.z), cvt_bf16(v.w));
        *(ushort4*)(&w_b[i * 4]) = o;
    }
    for (int i = gid; i < Bn * Un * (Dn / 4); i += stride) {
        int b = i / (Un * (Dn / 4));
        int rem = i - b * (Un * (Dn / 4));
        int u = rem >> 6;
        int k4 = rem & 63;
        int v = (u == 0) ? 0 : ((u <= Ln) ? ys[b * Ln + u - 1] : -1);
        float4 val = make_float4(0.f, 0.f, 0.f, 0.f);
        if (v >= 0) val = W4[(size_t)v * (Dn / 4) + k4];
        ushort4 o = make_ushort4(cvt_bf16(val.x), cvt_bf16(val.y), cvt_bf16(val.z), cvt_bf16(val.w));
        *(ushort4*)(&wg_b[i * 4]) = o;
    }
    for (int i = gid; i < Bn * Un; i += stride) {
        int b = i / Un;
        int u = i - b * Un;
        int v = (u == 0) ? 0 : ((u <= Ln) ? ys[b * Ln + u - 1] : -1);
        gbias[i] = (v >= 0) ? bias[v] : 0.0f;
    }
}

// ---------------- main GEMM: partial sums of exp over V ----------------
__global__ __launch_bounds__(256) void gemm_se(
    const unsigned short* __restrict__ hs_b, const unsigned short* __restrict__ w_b,
    const float* __restrict__ bias, float* __restrict__ sep)
{
    __shared__ __align__(16) short lsA[128 * 64];
    __shared__ __align__(16) short lsB[128 * 64];

    const int tid = threadIdx.x;
    const int lane = tid & 63;
    const int w = tid >> 6;
    const int lr = lane & 15;
    const int kq = lane >> 4;
    const int m0 = blockIdx.x * 128;
    const int n0 = blockIdx.y * 128;
    const int mw = w * 32;

    const int srow = lane >> 3;
    const int scol = (lane & 7) * 8;

    f32x4 acc[2][8];
    #pragma unroll
    for (int mf = 0; mf < 2; ++mf)
        #pragma unroll
        for (int nf = 0; nf < 8; ++nf)
            acc[mf][nf] = (f32x4){0.f, 0.f, 0.f, 0.f};

    for (int ks = 0; ks < 4; ++ks) {
        const int k0 = ks * 64;
        __syncthreads();
        #pragma unroll
        for (int j = 0; j < 4; ++j) {
            int c = w * 4 + j;
            int row = c * 8 + srow;
            gl_lds16(hs_b + (size_t)(m0 + row) * Dn + k0 + scol, (char*)lsA + c * 1024);
            gl_lds16(w_b  + (size_t)(n0 + row) * Dn + k0 + scol, (char*)lsB + c * 1024);
        }
        __syncthreads();

        #pragma unroll
        for (int sub = 0; sub < 2; ++sub) {
            short8 af[2], bf[8];
            #pragma unroll
            for (int mf = 0; mf < 2; ++mf)
                af[mf] = *(const short8*)(&lsA[(mw + mf * 16 + lr) * 64 + sub * 32 + kq * 8]);
            #pragma unroll
            for (int nf = 0; nf < 8; ++nf)
                bf[nf] = *(const short8*)(&lsB[(nf * 16 + lr) * 64 + sub * 32 + kq * 8]);
            #pragma unroll
            for (int mf = 0; mf < 2; ++mf)
                #pragma unroll
                for (int nf = 0; nf < 8; ++nf)
                    acc[mf][nf] = __builtin_amdgcn_mfma_f32_16x16x32_bf16(
                        af[mf], bf[nf], acc[mf][nf], 0, 0, 0);
        }
    }

    float bcol[8]; bool valid[8];
    #pragma unroll
    for (int nf = 0; nf < 8; ++nf) {
        int col = n0 + nf * 16 + lr;
        valid[nf] = (col < Vn);
        bcol[nf] = valid[nf] ? bias[col] : 0.0f;
    }
    #pragma unroll
    for (int mf = 0; mf < 2; ++mf) {
        #pragma unroll
        for (int r = 0; r < 4; ++r) {
            float s = 0.0f;
            #pragma unroll
            for (int nf = 0; nf < 8; ++nf)
                if (valid[nf]) s += __expf(acc[mf][nf][r] + bcol[nf]);
            #pragma unroll
            for (int off = 1; off < 16; off <<= 1) s += __shfl_xor(s, off, 64);
            if (lr == 0)
                sep[(size_t)blockIdx.y * Mtot + m0 + mw + mf * 16 + kq * 4 + r] = s;
        }
    }
}

// ---------------- gathered-label GEMM -> normalized log2-probs ----------------
// glp[b][t][u] = (logit + bias - lse) * (1/ln2)   [log2 domain for ctc_fwd]
__global__ __launch_bounds__(256) void gemm_gather(
    const unsigned short* __restrict__ hs_b, const unsigned short* __restrict__ wg_b,
    const float* __restrict__ gbias, const float* __restrict__ sep,
    float* __restrict__ glp)
{
    __shared__ short lsA[128 * LP];
    __shared__ short lsB[Un * LP];
    __shared__ float red2[128][2];
    __shared__ float sh_lse[128];

    const int tid = threadIdx.x;
    const int lane = tid & 63;
    const int w = tid >> 6;
    const int lr = lane & 15;
    const int kq = lane >> 4;
    const int m0 = blockIdx.x * 128;
    const int b = blockIdx.y;
    const int mw = w * 32;

    f32x4 acc[2][5];
    #pragma unroll
    for (int mf = 0; mf < 2; ++mf)
        #pragma unroll
        for (int nf = 0; nf < 5; ++nf)
            acc[mf][nf] = (f32x4){0.f, 0.f, 0.f, 0.f};

    for (int ks = 0; ks < 4; ++ks) {
        const int k0 = ks * 64;
        float4 ga[4];
        #pragma unroll
        for (int j = 0; j < 4; ++j) {
            int ch = tid + 256 * j;
            int row = ch >> 3, off = (ch & 7) * 8;
            ga[j] = *(const float4*)(hs_b + (size_t)(b * Tn + m0 + row) * Dn + k0 + off);
        }
        float4 gbv[3];
        int nb = 0;
        for (int ch = tid; ch < Un * 8; ch += 256, ++nb) {
            int row = ch >> 3, off = (ch & 7) * 8;
            gbv[nb] = *(const float4*)(wg_b + (size_t)(b * Un + row) * Dn + k0 + off);
        }
        __syncthreads();
        #pragma unroll
        for (int j = 0; j < 4; ++j) {
            int ch = tid + 256 * j;
            int row = ch >> 3, off = (ch & 7) * 8;
            *(float4*)(&lsA[row * LP + off]) = ga[j];
        }
        nb = 0;
        for (int ch = tid; ch < Un * 8; ch += 256, ++nb) {
            int row = ch >> 3, off = (ch & 7) * 8;
            *(float4*)(&lsB[row * LP + off]) = gbv[nb];
        }
        __syncthreads();

        #pragma unroll
        for (int sub = 0; sub < 2; ++sub) {
            short8 af[2], bf[5];
            #pragma unroll
            for (int mf = 0; mf < 2; ++mf)
                af[mf] = *(const short8*)(&lsA[(mw + mf * 16 + lr) * LP + sub * 32 + kq * 8]);
            #pragma unroll
            for (int nf = 0; nf < 5; ++nf)
                bf[nf] = *(const short8*)(&lsB[(nf * 16 + lr) * LP + sub * 32 + kq * 8]);
            #pragma unroll
            for (int mf = 0; mf < 2; ++mf)
                #pragma unroll
                for (int nf = 0; nf < 5; ++nf)
                    acc[mf][nf] = __builtin_amdgcn_mfma_f32_16x16x32_bf16(
                        af[mf], bf[nf], acc[mf][nf], 0, 0, 0);
        }
    }

    {
        int r = tid >> 1, half = tid & 1;
        int g = b * Tn + m0 + r;
        float s = 0.0f;
        #pragma unroll
        for (int j = 0; j < 17; ++j) {
            int c = half * 17 + j;
            s += sep[(size_t)c * Mtot + g];
        }
        red2[r][half] = s;
    }
    __syncthreads();
    if (tid < 128) sh_lse[tid] = __logf(red2[tid][0] + red2[tid][1]);
    __syncthreads();

    #pragma unroll
    for (int mf = 0; mf < 2; ++mf) {
        #pragma unroll
        for (int r = 0; r < 4; ++r) {
            int lrow = mw + mf * 16 + kq * 4 + r;
            int t = m0 + lrow;
            float lse = sh_lse[lrow];
            #pragma unroll
            for (int nf = 0; nf < 5; ++nf) {
                int u = nf * 16 + lr;
                glp[((size_t)(b * Tn + t)) * Un + u] =
                    (acc[mf][nf][r] + gbias[b * Un + u] - lse) * INV_LN2;
            }
        }
    }
}

// ---------------- CTC forward recursion (log2 domain, LDS-staged) ----------------
// One block per batch element; 4 waves cooperatively stage 64-step chunks of
// glp into double-buffered LDS (global latency hidden 64 steps ahead), all
// waves run the recursion redundantly. Lane l: aOdd=alpha[2l+1],
// aEven=alpha[2l+2]; alpha[0] tracked wave-redundantly. Cross-lane via DPP.
__global__ __launch_bounds__(256) void ctc_fwd(
    const float* __restrict__ glp, const int* __restrict__ ys,
    const int* __restrict__ hlens, const int* __restrict__ ylens,
    float* __restrict__ ll_out)
{
    __shared__ float ls[2][64 * CS + 4];

    const int b = blockIdx.x;
    const int tid = threadIdx.x;
    const int l = tid & 63;

    const int hl = hlens[b];
    int yl  = ys[b * Ln + l];
    int ylm = (l >= 1) ? ys[b * Ln + l - 1] : -1;
    const bool allow1 = (l >= 1) && (yl != ylm);

    const float* gb = glp + (size_t)b * Tn * Un;

    // stage chunk 0
    #pragma unroll
    for (int j = 0; j < 4; ++j) {
        int i = tid + j * 256;
        int tt = i >> 4, u4 = (i & 15) * 4;
        *(float4*)(&ls[0][tt * CS + u4]) = *(const float4*)(gb + tt * 80 + u4);
    }
    if (tid < 64) ls[0][tid * CS + 64] = gb[tid * 80 + 64];
    __syncthreads();

    // init t=0 (log2 domain)
    float A0    = ls[0][0];
    float aOdd  = (l == 0) ? ls[0][1] : NEG;
    float aEven = NEG;

    float4 r4[4];
    float r1 = 0.0f;

    for (int c = 0; c < 8; ++c) {
        if (c < 7) {
            const float* src = gb + (size_t)(c + 1) * 64 * 80;
            #pragma unroll
            for (int j = 0; j < 4; ++j) {
                int i = tid + j * 256;
                int tt = i >> 4, u4 = (i & 15) * 4;
                r4[j] = *(const float4*)(src + tt * 80 + u4);
            }
            if (tid < 64) r1 = src[tid * 80 + 64];
        }

        const float* buf = ls[c & 1];
        const int tstart = (c == 0) ? 1 : 0;
        const int tbase = c * 64;

        // 1-step register rotation for the two LDS reads (ds latency off-chain)
        float lpb_c = buf[tstart * CS];
        float lpl_c = buf[tstart * CS + 1 + l];

        for (int tt = tstart; tt < 64; ++tt) {
            float lpb_n = 0.0f, lpl_n = 0.0f;
            if (tt + 1 < 64) {
                lpb_n = buf[(tt + 1) * CS];
                lpl_n = buf[(tt + 1) * CS + 1 + l];
            }

            float pOdd  = dpp_shr1(aOdd, NEG);   // alpha[2l-1]; lane0 -> NEG
            float pEven = dpp_shr1(aEven, A0);   // alpha[2l];   lane0 -> alpha[0]
            float pA = allow1 ? pOdd : NEG;

            // odd state s=2l+1
            float m1 = fmaxf(fmaxf(aOdd, pEven), pA);
            float s1 = ex2(aOdd - m1) + ex2(pEven - m1) + ex2(pA - m1);
            float uOdd = (m1 + lpl_c) + lg2(s1);

            // even state s=2l+2 (lane-local)
            float m2 = fmaxf(aEven, aOdd);
            float s2 = ex2(aEven - m2) + ex2(aOdd - m2);
            float uEven = (m2 + lpb_c) + lg2(s2);

            float uA0 = A0 + lpb_c;

            bool act = (tbase + tt) < hl;
            aOdd  = act ? uOdd  : aOdd;
            aEven = act ? uEven : aEven;
            A0    = act ? uA0   : A0;

            lpb_c = lpb_n;
            lpl_c = lpl_n;
        }

        if (c < 7) {
            float* dst = ls[(c + 1) & 1];
            #pragma unroll
            for (int j = 0; j < 4; ++j) {
                int i = tid + j * 256;
                int tt = i >> 4, u4 = (i & 15) * 4;
                *(float4*)(&dst[tt * CS + u4]) = r4[j];
            }
            if (tid < 64) dst[tid * CS + 64] = r1;
        }
        __syncthreads();
    }

    int L = ylens[b];
    if (tid == (L - 1)) {   // wave 0, lane L-1 (L in [32,64])
        // alpha[2L] = aEven, alpha[2L-1] = aOdd (both on lane L-1)
        float m = fmaxf(aOdd, aEven);
        float ll2 = m + lg2(ex2(aOdd - m) + ex2(aEven - m));
        ll_out[b] = ll2 * LN2;
    }
}

__global__ void finalize(const float* __restrict__ ll, float* __restrict__ out) {
    if (threadIdx.x == 0 && blockIdx.x == 0) {
        float s = 0.0f;
        #pragma unroll
        for (int b = 0; b < Bn; ++b) s += ll[b];
        out[0] = -s / (float)Bn;
    }
}

extern "C" void kernel_launch(void* const* d_in, const int* in_sizes, int n_in,
                              void* d_out, int out_size, void* d_ws, size_t ws_size,
                              hipStream_t stream) {
    const float* hs    = (const float*)d_in[0];
    const int*   hlens = (const int*)d_in[1];
    const int*   ys    = (const int*)d_in[2];
    const int*   ylens = (const int*)d_in[3];
    const float* W     = (const float*)d_in[4];
    const float* bias  = (const float*)d_in[5];
    float* out = (float*)d_out;

    char* ws = (char*)d_ws;
    unsigned short* hs_b = (unsigned short*)(ws);                       // 4,194,304 B
    unsigned short* w_b  = (unsigned short*)(ws + 4194304);             // 2,228,224 B
    unsigned short* wg_b = (unsigned short*)(ws + 6422528);             //   655,360 B
    float* glp   = (float*)(ws + 7077888);                              // 2,621,440 B
    float* sep   = (float*)(ws + 9699328);                              // 1,114,112 B
    float* gbias = (float*)(ws + 10813440);                             //     5,120 B
    float* ll    = (float*)(ws + 10818560);                             //        64 B

    conv<<<1024, 256, 0, stream>>>(hs, W, bias, ys, hs_b, w_b, wg_b, gbias);
    gemm_se<<<dim3(64, NCB), 256, 0, stream>>>(hs_b, w_b, bias, sep);
    gemm_gather<<<dim3(4, 16), 256, 0, stream>>>(hs_b, wg_b, gbias, sep, glp);
    ctc_fwd<<<Bn, 256, 0, stream>>>(glp, ys, hlens, ylens, ll);
    finalize<<<1, 64, 0, stream>>>(ll, out);
}

// Round 10
// 164.801 us; speedup vs baseline: 1.8698x; 1.2349x over previous
//
#include <hip/hip_runtime.h>

#define NEG (-1e30f)

constexpr int Bn = 16;
constexpr int Tn = 512;
constexpr int Dn = 256;
constexpr int Vn = 4233;
constexpr int Vp = 4352;   // V padded to 34*128
constexpr int Ln = 64;     // LMAX
constexpr int Un = 80;     // padded gathered-label count (65 -> 80 = 5*16)
constexpr int LP = 72;     // LDS row stride in bf16 for gemm_gather (64 + 8 pad)
constexpr int CS = 68;     // ctc LDS row stride in floats
constexpr int NCB = 34;    // number of 128-wide column blocks in gemm_se
constexpr int Mtot = Bn * Tn;  // 8192

#define LN2 0.6931471805599453f

typedef __attribute__((ext_vector_type(8))) short short8;
typedef __attribute__((ext_vector_type(4))) float f32x4;

// native base-2 log (v_log_f32)
__device__ __forceinline__ float lg2(float x) { return __builtin_amdgcn_logf(x); }

__device__ __forceinline__ unsigned short cvt_bf16(float f) {
    unsigned int u = __float_as_uint(f);
    u = (u + 0x7fffu + ((u >> 16) & 1u)) >> 16;
    return (unsigned short)u;
}

// async global->LDS, 16B per lane; LDS dest is wave-uniform base + lane*16
__device__ __forceinline__ void gl_lds16(const void* g, void* l) {
    __builtin_amdgcn_global_load_lds(
        (const __attribute__((address_space(1))) void*)g,
        (__attribute__((address_space(3))) void*)l,
        16, 0, 0);
}

// f64 value from lane-1 (wave_shr:1); lane 0 takes `edge`
__device__ __forceinline__ double dpp_shr1_d(double v, double edge) {
    int lo = __builtin_amdgcn_update_dpp(
        __double2loint(edge), __double2loint(v), 0x138, 0xF, 0xF, false);
    int hi = __builtin_amdgcn_update_dpp(
        __double2hiint(edge), __double2hiint(v), 0x138, 0xF, 0xF, false);
    return __hiloint2double(hi, lo);
}

template <int CTRL>
__device__ __forceinline__ float dpp_max(float x) {
    float y = __int_as_float(__builtin_amdgcn_update_dpp(
        __float_as_int(x), __float_as_int(x), CTRL, 0xF, 0xF, false));
    return fmaxf(x, y);
}

// wave-wide max (f32), uniform result via readlane 63
__device__ __forceinline__ float wave_max(float x) {
    x = dpp_max<0x111>(x);   // row_shr:1
    x = dpp_max<0x112>(x);   // row_shr:2
    x = dpp_max<0x114>(x);   // row_shr:4
    x = dpp_max<0x118>(x);   // row_shr:8
    x = dpp_max<0x142>(x);   // row_bcast:15
    x = dpp_max<0x143>(x);   // row_bcast:31
    return __int_as_float(__builtin_amdgcn_readlane(__float_as_int(x), 63));
}

// rescale f64 states so wave max ~ [1,2); accumulate exponent in etot.
// Called every 8 steps: max decays ~100 bits/window, so the f32 convert
// of the wave max stays normal.
__device__ __forceinline__ void renorm_d(double& aOdd, double& aEven, double& A0, int& etot) {
    double md = fmax(fmax(aOdd, aEven), A0);
    float m = wave_max((float)md);
    int e = (int)((__float_as_uint(m) >> 23) & 0xFFu) - 127;
    if (e < -126) e = -126;
    aOdd  = ldexp(aOdd, -e);
    aEven = ldexp(aEven, -e);
    A0    = ldexp(A0, -e);
    etot += e;
}

// ---------------- conversion / gather prep ----------------
__global__ __launch_bounds__(256) void conv(
    const float* __restrict__ hs, const float* __restrict__ W,
    const float* __restrict__ bias, const int* __restrict__ ys,
    unsigned short* __restrict__ hs_b, unsigned short* __restrict__ w_b,
    unsigned short* __restrict__ wg_b, float* __restrict__ gbias)
{
    const int gid = blockIdx.x * 256 + threadIdx.x;
    const int stride = gridDim.x * 256;
    const float4* hs4 = (const float4*)hs;
    const float4* W4  = (const float4*)W;

    for (int i = gid; i < (Bn * Tn * Dn) / 4; i += stride) {
        float4 v = hs4[i];
        ushort4 o = make_ushort4(cvt_bf16(v.x), cvt_bf16(v.y), cvt_bf16(v.z), cvt_bf16(v.w));
        *(ushort4*)(&hs_b[i * 4]) = o;
    }
    for (int i = gid; i < Vp * (Dn / 4); i += stride) {
        int row = i >> 6;
        float4 v = make_float4(0.f, 0.f, 0.f, 0.f);
        if (row < Vn) v = W4[i];
        ushort4 o = make_ushort4(cvt_bf16(v.x), cvt_bf16(v.y), cvt_bf16(v.z), cvt_bf16(v.w));
        *(ushort4*)(&w_b[i * 4]) = o;
    }
    for (int i = gid; i < Bn * Un * (Dn / 4); i += stride) {
        int b = i / (Un * (Dn / 4));
        int rem = i - b * (Un * (Dn / 4));
        int u = rem >> 6;
        int k4 = rem & 63;
        int v = (u == 0) ? 0 : ((u <= Ln) ? ys[b * Ln + u - 1] : -1);
        float4 val = make_float4(0.f, 0.f, 0.f, 0.f);
        if (v >= 0) val = W4[(size_t)v * (Dn / 4) + k4];
        ushort4 o = make_ushort4(cvt_bf16(val.x), cvt_bf16(val.y), cvt_bf16(val.z), cvt_bf16(val.w));
        *(ushort4*)(&wg_b[i * 4]) = o;
    }
    for (int i = gid; i < Bn * Un; i += stride) {
        int b = i / Un;
        int u = i - b * Un;
        int v = (u == 0) ? 0 : ((u <= Ln) ? ys[b * Ln + u - 1] : -1);
        gbias[i] = (v >= 0) ? bias[v] : 0.0f;
    }
}

// ---------------- main GEMM: partial sums of exp over V ----------------
__global__ __launch_bounds__(256) void gemm_se(
    const unsigned short* __restrict__ hs_b, const unsigned short* __restrict__ w_b,
    const float* __restrict__ bias, float* __restrict__ sep)
{
    __shared__ __align__(16) short lsA[128 * 64];
    __shared__ __align__(16) short lsB[128 * 64];

    const int tid = threadIdx.x;
    const int lane = tid & 63;
    const int w = tid >> 6;
    const int lr = lane & 15;
    const int kq = lane >> 4;
    const int m0 = blockIdx.x * 128;
    const int n0 = blockIdx.y * 128;
    const int mw = w * 32;

    const int srow = lane >> 3;
    const int scol = (lane & 7) * 8;

    f32x4 acc[2][8];
    #pragma unroll
    for (int mf = 0; mf < 2; ++mf)
        #pragma unroll
        for (int nf = 0; nf < 8; ++nf)
            acc[mf][nf] = (f32x4){0.f, 0.f, 0.f, 0.f};

    for (int ks = 0; ks < 4; ++ks) {
        const int k0 = ks * 64;
        __syncthreads();
        #pragma unroll
        for (int j = 0; j < 4; ++j) {
            int c = w * 4 + j;
            int row = c * 8 + srow;
            gl_lds16(hs_b + (size_t)(m0 + row) * Dn + k0 + scol, (char*)lsA + c * 1024);
            gl_lds16(w_b  + (size_t)(n0 + row) * Dn + k0 + scol, (char*)lsB + c * 1024);
        }
        __syncthreads();

        #pragma unroll
        for (int sub = 0; sub < 2; ++sub) {
            short8 af[2], bf[8];
            #pragma unroll
            for (int mf = 0; mf < 2; ++mf)
                af[mf] = *(const short8*)(&lsA[(mw + mf * 16 + lr) * 64 + sub * 32 + kq * 8]);
            #pragma unroll
            for (int nf = 0; nf < 8; ++nf)
                bf[nf] = *(const short8*)(&lsB[(nf * 16 + lr) * 64 + sub * 32 + kq * 8]);
            #pragma unroll
            for (int mf = 0; mf < 2; ++mf)
                #pragma unroll
                for (int nf = 0; nf < 8; ++nf)
                    acc[mf][nf] = __builtin_amdgcn_mfma_f32_16x16x32_bf16(
                        af[mf], bf[nf], acc[mf][nf], 0, 0, 0);
        }
    }

    float bcol[8]; bool valid[8];
    #pragma unroll
    for (int nf = 0; nf < 8; ++nf) {
        int col = n0 + nf * 16 + lr;
        valid[nf] = (col < Vn);
        bcol[nf] = valid[nf] ? bias[col] : 0.0f;
    }
    #pragma unroll
    for (int mf = 0; mf < 2; ++mf) {
        #pragma unroll
        for (int r = 0; r < 4; ++r) {
            float s = 0.0f;
            #pragma unroll
            for (int nf = 0; nf < 8; ++nf)
                if (valid[nf]) s += __expf(acc[mf][nf][r] + bcol[nf]);
            #pragma unroll
            for (int off = 1; off < 16; off <<= 1) s += __shfl_xor(s, off, 64);
            if (lr == 0)
                sep[(size_t)blockIdx.y * Mtot + m0 + mw + mf * 16 + kq * 4 + r] = s;
        }
    }
}

// ---------------- gathered-label GEMM -> normalized LINEAR probs ----------------
// glp[b][t][u] = exp(logit + bias - lse)
__global__ __launch_bounds__(256) void gemm_gather(
    const unsigned short* __restrict__ hs_b, const unsigned short* __restrict__ wg_b,
    const float* __restrict__ gbias, const float* __restrict__ sep,
    float* __restrict__ glp)
{
    __shared__ short lsA[128 * LP];
    __shared__ short lsB[Un * LP];
    __shared__ float red2[128][2];
    __shared__ float sh_lse[128];

    const int tid = threadIdx.x;
    const int lane = tid & 63;
    const int w = tid >> 6;
    const int lr = lane & 15;
    const int kq = lane >> 4;
    const int m0 = blockIdx.x * 128;
    const int b = blockIdx.y;
    const int mw = w * 32;

    f32x4 acc[2][5];
    #pragma unroll
    for (int mf = 0; mf < 2; ++mf)
        #pragma unroll
        for (int nf = 0; nf < 5; ++nf)
            acc[mf][nf] = (f32x4){0.f, 0.f, 0.f, 0.f};

    for (int ks = 0; ks < 4; ++ks) {
        const int k0 = ks * 64;
        float4 ga[4];
        #pragma unroll
        for (int j = 0; j < 4; ++j) {
            int ch = tid + 256 * j;
            int row = ch >> 3, off = (ch & 7) * 8;
            ga[j] = *(const float4*)(hs_b + (size_t)(b * Tn + m0 + row) * Dn + k0 + off);
        }
        float4 gbv[3];
        int nb = 0;
        for (int ch = tid; ch < Un * 8; ch += 256, ++nb) {
            int row = ch >> 3, off = (ch & 7) * 8;
            gbv[nb] = *(const float4*)(wg_b + (size_t)(b * Un + row) * Dn + k0 + off);
        }
        __syncthreads();
        #pragma unroll
        for (int j = 0; j < 4; ++j) {
            int ch = tid + 256 * j;
            int row = ch >> 3, off = (ch & 7) * 8;
            *(float4*)(&lsA[row * LP + off]) = ga[j];
        }
        nb = 0;
        for (int ch = tid; ch < Un * 8; ch += 256, ++nb) {
            int row = ch >> 3, off = (ch & 7) * 8;
            *(float4*)(&lsB[row * LP + off]) = gbv[nb];
        }
        __syncthreads();

        #pragma unroll
        for (int sub = 0; sub < 2; ++sub) {
            short8 af[2], bf[5];
            #pragma unroll
            for (int mf = 0; mf < 2; ++mf)
                af[mf] = *(const short8*)(&lsA[(mw + mf * 16 + lr) * LP + sub * 32 + kq * 8]);
            #pragma unroll
            for (int nf = 0; nf < 5; ++nf)
                bf[nf] = *(const short8*)(&lsB[(nf * 16 + lr) * LP + sub * 32 + kq * 8]);
            #pragma unroll
            for (int mf = 0; mf < 2; ++mf)
                #pragma unroll
                for (int nf = 0; nf < 5; ++nf)
                    acc[mf][nf] = __builtin_amdgcn_mfma_f32_16x16x32_bf16(
                        af[mf], bf[nf], acc[mf][nf], 0, 0, 0);
        }
    }

    {
        int r = tid >> 1, half = tid & 1;
        int g = b * Tn + m0 + r;
        float s = 0.0f;
        #pragma unroll
        for (int j = 0; j < 17; ++j) {
            int c = half * 17 + j;
            s += sep[(size_t)c * Mtot + g];
        }
        red2[r][half] = s;
    }
    __syncthreads();
    if (tid < 128) sh_lse[tid] = __logf(red2[tid][0] + red2[tid][1]);
    __syncthreads();

    #pragma unroll
    for (int mf = 0; mf < 2; ++mf) {
        #pragma unroll
        for (int r = 0; r < 4; ++r) {
            int lrow = mw + mf * 16 + kq * 4 + r;
            int t = m0 + lrow;
            float lse = sh_lse[lrow];
            #pragma unroll
            for (int nf = 0; nf < 5; ++nf) {
                int u = nf * 16 + lr;
                glp[((size_t)(b * Tn + t)) * Un + u] =
                    __expf(acc[mf][nf][r] + gbias[b * Un + u] - lse);
            }
        }
    }
}

// ---------------- CTC forward recursion (LINEAR f64, renormalized) ----------------
// One block/batch; 4 waves stage 64-step chunks of linear f32 probs into
// double-buffered LDS; all waves run the recursion redundantly in f64
// (1022-bit exponent range covers CTC's cross-state spread; the f32
// wave-shared scheme flushed the answer states -> round-9 inf).
// Lane l: aOdd=alpha[2l+1], aEven=alpha[2l+2]; alpha[0]=A0 wave-redundant.
__global__ __launch_bounds__(256) void ctc_fwd(
    const float* __restrict__ glp, const int* __restrict__ ys,
    const int* __restrict__ hlens, const int* __restrict__ ylens,
    float* __restrict__ ll_out)
{
    __shared__ float ls[2][64 * CS + 4];

    const int b = blockIdx.x;
    const int tid = threadIdx.x;
    const int l = tid & 63;

    const int hl = hlens[b];
    int yl  = ys[b * Ln + l];
    int ylm = (l >= 1) ? ys[b * Ln + l - 1] : -1;
    const double allowMul = ((l >= 1) && (yl != ylm)) ? 1.0 : 0.0;

    const float* gb = glp + (size_t)b * Tn * Un;

    // stage chunk 0: row tt <-> timestep t = 1 + tt
    #pragma unroll
    for (int j = 0; j < 4; ++j) {
        int i = tid + j * 256;
        int tt = i >> 4, u4 = (i & 15) * 4;
        *(float4*)(&ls[0][tt * CS + u4]) = *(const float4*)(gb + (size_t)(1 + tt) * Un + u4);
    }
    if (tid < 64) ls[0][tid * CS + 64] = gb[(size_t)(1 + tid) * Un + 64];
    __syncthreads();

    // t=0 init (linear, f64)
    double A0    = (double)gb[0];
    double aOdd  = (l == 0) ? (double)gb[1] : 0.0;
    double aEven = 0.0;
    int etot = 0;

    float4 r4[4];
    float r1 = 0.0f;

#define STEP(PL, PB) do { \
        double pOdd  = dpp_shr1_d(aOdd, 0.0); \
        double pEven = dpp_shr1_d(aEven, A0); \
        double uOdd  = (aOdd + pEven + pOdd * allowMul) * (double)(PL); \
        double uEven = (aEven + aOdd) * (double)(PB); \
        A0 *= (double)(PB); \
        aOdd = uOdd; aEven = uEven; \
    } while (0)

    for (int c = 0; c < 8; ++c) {
        // prefetch chunk c+1 into registers (stored to LDS after compute)
        if (c < 7) {
            const int tb = 1 + (c + 1) * 64;
            #pragma unroll
            for (int j = 0; j < 4; ++j) {
                int i = tid + j * 256;
                int tt = i >> 4, u4 = (i & 15) * 4;
                r4[j] = (tb + tt < Tn)
                    ? *(const float4*)(gb + (size_t)(tb + tt) * Un + u4)
                    : make_float4(0.f, 0.f, 0.f, 0.f);
            }
            if (tid < 64)
                r1 = (tb + tid < Tn) ? gb[(size_t)(tb + tid) * Un + 64] : 0.0f;
        }

        const float* buf = ls[c & 1];
        int lim = hl - 1 - c * 64;          // valid steps in this chunk
        if (lim > 64) lim = 64;

        if (lim > 0) {
            float plC[8], pbC[8];
            #pragma unroll
            for (int j = 0; j < 8; ++j) {
                pbC[j] = buf[j * CS];
                plC[j] = buf[j * CS + 1 + l];
            }
            int tt = 0;
            for (; tt + 8 <= lim; tt += 8) {
                float plN[8], pbN[8];
                const bool more = (tt + 8 < 64);
                if (more) {
                    #pragma unroll
                    for (int j = 0; j < 8; ++j) {
                        pbN[j] = buf[(tt + 8 + j) * CS];
                        plN[j] = buf[(tt + 8 + j) * CS + 1 + l];
                    }
                }
                #pragma unroll
                for (int j = 0; j < 8; ++j) STEP(plC[j], pbC[j]);
                renorm_d(aOdd, aEven, A0, etot);
                if (more) {
                    #pragma unroll
                    for (int j = 0; j < 8; ++j) { plC[j] = plN[j]; pbC[j] = pbN[j]; }
                }
            }
            if (tt < lim) {
                for (int j = 0; tt < lim; ++tt, ++j) STEP(plC[j], pbC[j]);
                renorm_d(aOdd, aEven, A0, etot);
            }
        }

        if (c < 7) {
            float* dst = ls[(c + 1) & 1];
            #pragma unroll
            for (int j = 0; j < 4; ++j) {
                int i = tid + j * 256;
                int tt2 = i >> 4, u4 = (i & 15) * 4;
                *(float4*)(&dst[tt2 * CS + u4]) = r4[j];
            }
            if (tid < 64) dst[tid * CS + 64] = r1;
        }
        __syncthreads();
    }
#undef STEP

    int L = ylens[b];
    if (tid == (L - 1)) {    // wave 0, lane L-1 holds alpha[2L-1], alpha[2L]
        double s = aOdd + aEven;            // true value = s * 2^etot
        int hi = __double2hiint(s);
        int es = ((hi >> 20) & 0x7FF) - 1023;
        double man = ldexp(s, -es);         // [1,2)
        float ll2 = lg2((float)man) + (float)(es + etot);
        ll_out[b] = ll2 * LN2;
    }
}

__global__ void finalize(const float* __restrict__ ll, float* __restrict__ out) {
    if (threadIdx.x == 0 && blockIdx.x == 0) {
        float s = 0.0f;
        #pragma unroll
        for (int b = 0; b < Bn; ++b) s += ll[b];
        out[0] = -s / (float)Bn;
    }
}

extern "C" void kernel_launch(void* const* d_in, const int* in_sizes, int n_in,
                              void* d_out, int out_size, void* d_ws, size_t ws_size,
                              hipStream_t stream) {
    const float* hs    = (const float*)d_in[0];
    const int*   hlens = (const int*)d_in[1];
    const int*   ys    = (const int*)d_in[2];
    const int*   ylens = (const int*)d_in[3];
    const float* W     = (const float*)d_in[4];
    const float* bias  = (const float*)d_in[5];
    float* out = (float*)d_out;

    char* ws = (char*)d_ws;
    unsigned short* hs_b = (unsigned short*)(ws);                       // 4,194,304 B
    unsigned short* w_b  = (unsigned short*)(ws + 4194304);             // 2,228,224 B
    unsigned short* wg_b = (unsigned short*)(ws + 6422528);             //   655,360 B
    float* glp   = (float*)(ws + 7077888);                              // 2,621,440 B
    float* sep   = (float*)(ws + 9699328);                              // 1,114,112 B
    float* gbias = (float*)(ws + 10813440);                             //     5,120 B
    float* ll    = (float*)(ws + 10818560);                             //        64 B

    conv<<<1024, 256, 0, stream>>>(hs, W, bias, ys, hs_b, w_b, wg_b, gbias);
    gemm_se<<<dim3(64, NCB), 256, 0, stream>>>(hs_b, w_b, bias, sep);
    gemm_gather<<<dim3(4, 16), 256, 0, stream>>>(hs_b, wg_b, gbias, sep, glp);
    ctc_fwd<<<Bn, 256, 0, stream>>>(glp, ys, hlens, ylens, ll);
    finalize<<<1, 64, 0, stream>>>(ll, out);
}

// Round 11
// 146.863 us; speedup vs baseline: 2.0982x; 1.1221x over previous
//
#include <hip/hip_runtime.h>

constexpr int Bn = 16;
constexpr int Tn = 512;
constexpr int Dn = 256;
constexpr int Vn = 4233;
constexpr int Vp = 4352;   // V padded to 34*128
constexpr int Ln = 64;     // LMAX
constexpr int Un = 80;     // glg2 row stride (65 used)
constexpr int CS = 68;     // ctc LDS row stride in floats
constexpr int NCB = 34;    // number of 128-wide vocab column blocks
constexpr int Mtot = Bn * Tn;  // 8192

#define LN2     0.6931471805599453f
#define INV_LN2 1.4426950408889634f

typedef __attribute__((ext_vector_type(8))) short short8;
typedef __attribute__((ext_vector_type(4))) float f32x4;

__device__ __forceinline__ float lg2(float x) { return __builtin_amdgcn_logf(x); }
__device__ __forceinline__ float ex2(float x) { return __builtin_amdgcn_exp2f(x); }

__device__ __forceinline__ unsigned short cvt_bf16(float f) {
    unsigned int u = __float_as_uint(f);
    u = (u + 0x7fffu + ((u >> 16) & 1u)) >> 16;
    return (unsigned short)u;
}

// async global->LDS, 16B per lane; LDS dest is wave-uniform base + lane*16
__device__ __forceinline__ void gl_lds16(const void* g, void* l) {
    __builtin_amdgcn_global_load_lds(
        (const __attribute__((address_space(1))) void*)g,
        (__attribute__((address_space(3))) void*)l,
        16, 0, 0);
}

// f64 value from lane-1 (wave_shr:1); lane 0 takes `edge`
__device__ __forceinline__ double dpp_shr1_d(double v, double edge) {
    int lo = __builtin_amdgcn_update_dpp(
        __double2loint(edge), __double2loint(v), 0x138, 0xF, 0xF, false);
    int hi = __builtin_amdgcn_update_dpp(
        __double2hiint(edge), __double2hiint(v), 0x138, 0xF, 0xF, false);
    return __hiloint2double(hi, lo);
}

template <int CTRL>
__device__ __forceinline__ float dpp_max(float x) {
    float y = __int_as_float(__builtin_amdgcn_update_dpp(
        __float_as_int(x), __float_as_int(x), CTRL, 0xF, 0xF, false));
    return fmaxf(x, y);
}

__device__ __forceinline__ float wave_max(float x) {
    x = dpp_max<0x111>(x);
    x = dpp_max<0x112>(x);
    x = dpp_max<0x114>(x);
    x = dpp_max<0x118>(x);
    x = dpp_max<0x142>(x);   // row_bcast:15
    x = dpp_max<0x143>(x);   // row_bcast:31
    return __int_as_float(__builtin_amdgcn_readlane(__float_as_int(x), 63));
}

__device__ __forceinline__ void renorm_d(double& aOdd, double& aEven, double& A0, int& etot) {
    double md = fmax(fmax(aOdd, aEven), A0);
    float m = wave_max((float)md);
    int e = (int)((__float_as_uint(m) >> 23) & 0xFFu) - 127;
    if (e < -126) e = -126;
    aOdd  = ldexp(aOdd, -e);
    aEven = ldexp(aEven, -e);
    A0    = ldexp(A0, -e);
    etot += e;
}

// ---------------- conversion / gather prep ----------------
__global__ __launch_bounds__(256) void conv(
    const float* __restrict__ hs, const float* __restrict__ W,
    const float* __restrict__ bias, const int* __restrict__ ys,
    unsigned short* __restrict__ hs_b, unsigned short* __restrict__ w_b,
    unsigned short* __restrict__ wg_b, float* __restrict__ gbias)
{
    const int gid = blockIdx.x * 256 + threadIdx.x;
    const int stride = gridDim.x * 256;
    const float4* hs4 = (const float4*)hs;
    const float4* W4  = (const float4*)W;

    for (int i = gid; i < (Bn * Tn * Dn) / 4; i += stride) {
        float4 v = hs4[i];
        ushort4 o = make_ushort4(cvt_bf16(v.x), cvt_bf16(v.y), cvt_bf16(v.z), cvt_bf16(v.w));
        *(ushort4*)(&hs_b[i * 4]) = o;
    }
    for (int i = gid; i < Vp * (Dn / 4); i += stride) {
        int row = i >> 6;
        float4 v = make_float4(0.f, 0.f, 0.f, 0.f);
        if (row < Vn) v = W4[i];
        ushort4 o = make_ushort4(cvt_bf16(v.x), cvt_bf16(v.y), cvt_bf16(v.z), cvt_bf16(v.w));
        *(ushort4*)(&w_b[i * 4]) = o;
    }
    // gathered label rows, padded to 128 rows/batch (rows 65..127 zero)
    for (int i = gid; i < Bn * 128 * (Dn / 4); i += stride) {
        int b = i / (128 * (Dn / 4));
        int rem = i - b * (128 * (Dn / 4));
        int u = rem >> 6;
        int k4 = rem & 63;
        int v = (u == 0) ? 0 : ((u <= Ln) ? ys[b * Ln + u - 1] : -1);
        float4 val = make_float4(0.f, 0.f, 0.f, 0.f);
        if (v >= 0) val = W4[(size_t)v * (Dn / 4) + k4];
        ushort4 o = make_ushort4(cvt_bf16(val.x), cvt_bf16(val.y), cvt_bf16(val.z), cvt_bf16(val.w));
        *(ushort4*)(&wg_b[i * 4]) = o;
    }
    for (int i = gid; i < Bn * 128; i += stride) {
        int b = i >> 7;
        int u = i & 127;
        int v = (u == 0) ? 0 : ((u <= Ln) ? ys[b * Ln + u - 1] : -1);
        gbias[i] = (v >= 0) ? bias[v] : 0.0f;
    }
}

// ---------------- unified GEMM ----------------
// grid (64, 35). y<34: 128x128 vocab tile -> partial expsum sep[y][row].
// y==34: gathered-label tile (per-batch wg_b) -> raw log2-logits glg2.
// LDS is XOR-swizzled: LDS[row][cg] = G[row][cg ^ (row&7)] (cg = 16B colgroup)
// so MFMA fragment reads are 2-way (free) instead of 16-way bank conflicted,
// while global_load_lds destinations stay contiguous.
__global__ __launch_bounds__(256) void gemm_se(
    const unsigned short* __restrict__ hs_b, const unsigned short* __restrict__ w_b,
    const unsigned short* __restrict__ wg_b, const float* __restrict__ bias,
    const float* __restrict__ gbias, float* __restrict__ sep,
    float* __restrict__ glg2)
{
    __shared__ __align__(16) short lsA[128 * 64];
    __shared__ __align__(16) short lsB[128 * 64];

    const int tid = threadIdx.x;
    const int lane = tid & 63;
    const int w = tid >> 6;
    const int lr = lane & 15;
    const int kq = lane >> 4;
    const int m0 = blockIdx.x * 128;
    const int mw = w * 32;
    const bool gather = (blockIdx.y == NCB);
    const int b = blockIdx.x >> 2;           // batch of this row tile

    // staging source swizzle: lane i covers (row=i>>3, cgL=i&7) of an 8-row chunk;
    // source colgroup = cgL ^ (row&7)
    const int srow = lane >> 3;
    const int scg  = (lane & 7) ^ (srow & 7);
    const int scol = scg * 8;                // bf16 offset within 64-wide row

    const unsigned short* Bp = gather ? (wg_b + (size_t)b * 128 * Dn)
                                      : (w_b + (size_t)blockIdx.y * 128 * Dn);

    f32x4 acc[2][8];
    #pragma unroll
    for (int mf = 0; mf < 2; ++mf)
        #pragma unroll
        for (int nf = 0; nf < 8; ++nf)
            acc[mf][nf] = (f32x4){0.f, 0.f, 0.f, 0.f};

    for (int ks = 0; ks < 4; ++ks) {
        const int k0 = ks * 64;
        __syncthreads();
        #pragma unroll
        for (int j = 0; j < 4; ++j) {
            int c = w * 4 + j;
            int row = c * 8 + srow;
            gl_lds16(hs_b + (size_t)(m0 + row) * Dn + k0 + scol, (char*)lsA + c * 1024);
            gl_lds16(Bp   + (size_t)row * Dn + k0 + scol,        (char*)lsB + c * 1024);
        }
        __syncthreads();

        #pragma unroll
        for (int sub = 0; sub < 2; ++sub) {
            short8 af[2], bf[8];
            #pragma unroll
            for (int mf = 0; mf < 2; ++mf) {
                int row = mw + mf * 16 + lr;
                int cg = (sub * 4 + kq) ^ (row & 7);
                af[mf] = *(const short8*)(&lsA[row * 64 + cg * 8]);
            }
            #pragma unroll
            for (int nf = 0; nf < 8; ++nf) {
                int row = nf * 16 + lr;
                int cg = (sub * 4 + kq) ^ (row & 7);
                bf[nf] = *(const short8*)(&lsB[row * 64 + cg * 8]);
            }
            #pragma unroll
            for (int mf = 0; mf < 2; ++mf)
                #pragma unroll
                for (int nf = 0; nf < 8; ++nf)
                    acc[mf][nf] = __builtin_amdgcn_mfma_f32_16x16x32_bf16(
                        af[mf], bf[nf], acc[mf][nf], 0, 0, 0);
        }
    }

    if (!gather) {
        const int n0 = blockIdx.y * 128;
        float bcol[8]; bool valid[8];
        #pragma unroll
        for (int nf = 0; nf < 8; ++nf) {
            int col = n0 + nf * 16 + lr;
            valid[nf] = (col < Vn);
            bcol[nf] = valid[nf] ? bias[col] : 0.0f;
        }
        #pragma unroll
        for (int mf = 0; mf < 2; ++mf) {
            #pragma unroll
            for (int r = 0; r < 4; ++r) {
                float s = 0.0f;
                #pragma unroll
                for (int nf = 0; nf < 8; ++nf)
                    if (valid[nf]) s += __expf(acc[mf][nf][r] + bcol[nf]);
                #pragma unroll
                for (int off = 1; off < 16; off <<= 1) s += __shfl_xor(s, off, 64);
                if (lr == 0)
                    sep[(size_t)blockIdx.y * Mtot + m0 + mw + mf * 16 + kq * 4 + r] = s;
            }
        }
    } else {
        // raw gathered logits in log2 domain: glg2[g][u] = (logit+gbias)/ln2
        #pragma unroll
        for (int mf = 0; mf < 2; ++mf) {
            #pragma unroll
            for (int nf = 0; nf < 5; ++nf) {
                int u = nf * 16 + lr;
                float gv = gbias[b * 128 + u];
                #pragma unroll
                for (int r = 0; r < 4; ++r) {
                    int g = m0 + mw + mf * 16 + kq * 4 + r;
                    glg2[(size_t)g * Un + u] = (acc[mf][nf][r] + gv) * INV_LN2;
                }
            }
        }
    }
}

// ---------------- lse reduction: lse2[g] = log2(sum_c sep[c][g]) ----------------
__global__ __launch_bounds__(256) void lse_red(
    const float* __restrict__ sep, float* __restrict__ lse2)
{
    int g = blockIdx.x * 256 + threadIdx.x;
    float s = 0.0f;
    #pragma unroll
    for (int c = 0; c < NCB; ++c) s += sep[(size_t)c * Mtot + g];
    lse2[g] = lg2(s);
}

// ---------------- CTC forward recursion (LINEAR f64, renormalized) ----------------
// Staging applies p = exp2(glg2 - lse2) (off the serial chain); recursion in
// f64 linear with per-8-step renorm. Lane l: aOdd=alpha[2l+1], aEven=alpha[2l+2].
__global__ __launch_bounds__(256) void ctc_fwd(
    const float* __restrict__ glg2, const float* __restrict__ lse2,
    const int* __restrict__ ys, const int* __restrict__ hlens,
    const int* __restrict__ ylens, float* __restrict__ ll_out)
{
    __shared__ float ls[2][64 * CS + 4];

    const int b = blockIdx.x;
    const int tid = threadIdx.x;
    const int l = tid & 63;

    const int hl = hlens[b];
    int yl  = ys[b * Ln + l];
    int ylm = (l >= 1) ? ys[b * Ln + l - 1] : -1;
    const double allowMul = ((l >= 1) && (yl != ylm)) ? 1.0 : 0.0;

    const float* gb2 = glg2 + (size_t)b * Tn * Un;
    const float* lsb = lse2 + (size_t)b * Tn;

    // stage chunk 0: row tt <-> timestep t = 1 + tt
    #pragma unroll
    for (int j = 0; j < 4; ++j) {
        int i = tid + j * 256;
        int tt = i >> 4, u4 = (i & 15) * 4;
        float4 v = *(const float4*)(gb2 + (size_t)(1 + tt) * Un + u4);
        float sub = lsb[1 + tt];
        v.x = ex2(v.x - sub); v.y = ex2(v.y - sub);
        v.z = ex2(v.z - sub); v.w = ex2(v.w - sub);
        *(float4*)(&ls[0][tt * CS + u4]) = v;
    }
    if (tid < 64)
        ls[0][tid * CS + 64] = ex2(gb2[(size_t)(1 + tid) * Un + 64] - lsb[1 + tid]);
    __syncthreads();

    // t=0 init (linear, f64)
    double A0    = (double)ex2(gb2[0] - lsb[0]);
    double aOdd  = (l == 0) ? (double)ex2(gb2[1] - lsb[0]) : 0.0;
    double aEven = 0.0;
    int etot = 0;

    float4 r4[4];
    float r1 = 0.0f;

#define STEP(PL, PB) do { \
        double pOdd  = dpp_shr1_d(aOdd, 0.0); \
        double pEven = dpp_shr1_d(aEven, A0); \
        double uOdd  = (aOdd + pEven + pOdd * allowMul) * (double)(PL); \
        double uEven = (aEven + aOdd) * (double)(PB); \
        A0 *= (double)(PB); \
        aOdd = uOdd; aEven = uEven; \
    } while (0)

    for (int c = 0; c < 8; ++c) {
        if (c < 7) {
            const int tb = 1 + (c + 1) * 64;
            #pragma unroll
            for (int j = 0; j < 4; ++j) {
                int i = tid + j * 256;
                int tt = i >> 4, u4 = (i & 15) * 4;
                if (tb + tt < Tn) {
                    float4 v = *(const float4*)(gb2 + (size_t)(tb + tt) * Un + u4);
                    float sub = lsb[tb + tt];
                    v.x = ex2(v.x - sub); v.y = ex2(v.y - sub);
                    v.z = ex2(v.z - sub); v.w = ex2(v.w - sub);
                    r4[j] = v;
                } else {
                    r4[j] = make_float4(0.f, 0.f, 0.f, 0.f);
                }
            }
            if (tid < 64)
                r1 = (tb + tid < Tn)
                    ? ex2(gb2[(size_t)(tb + tid) * Un + 64] - lsb[tb + tid]) : 0.0f;
        }

        const float* buf = ls[c & 1];
        int lim = hl - 1 - c * 64;
        if (lim > 64) lim = 64;

        if (lim > 0) {
            float plC[8], pbC[8];
            #pragma unroll
            for (int j = 0; j < 8; ++j) {
                pbC[j] = buf[j * CS];
                plC[j] = buf[j * CS + 1 + l];
            }
            int tt = 0;
            for (; tt + 8 <= lim; tt += 8) {
                float plN[8], pbN[8];
                const bool more = (tt + 8 < 64);
                if (more) {
                    #pragma unroll
                    for (int j = 0; j < 8; ++j) {
                        pbN[j] = buf[(tt + 8 + j) * CS];
                        plN[j] = buf[(tt + 8 + j) * CS + 1 + l];
                    }
                }
                #pragma unroll
                for (int j = 0; j < 8; ++j) STEP(plC[j], pbC[j]);
                renorm_d(aOdd, aEven, A0, etot);
                if (more) {
                    #pragma unroll
                    for (int j = 0; j < 8; ++j) { plC[j] = plN[j]; pbC[j] = pbN[j]; }
                }
            }
            if (tt < lim) {
                for (int j = 0; tt < lim; ++tt, ++j) STEP(plC[j], pbC[j]);
                renorm_d(aOdd, aEven, A0, etot);
            }
        }

        if (c < 7) {
            float* dst = ls[(c + 1) & 1];
            #pragma unroll
            for (int j = 0; j < 4; ++j) {
                int i = tid + j * 256;
                int tt2 = i >> 4, u4 = (i & 15) * 4;
                *(float4*)(&dst[tt2 * CS + u4]) = r4[j];
            }
            if (tid < 64) dst[tid * CS + 64] = r1;
        }
        __syncthreads();
    }
#undef STEP

    int L = ylens[b];
    if (tid == (L - 1)) {
        double s = aOdd + aEven;            // true value = s * 2^etot
        int hi = __double2hiint(s);
        int es = ((hi >> 20) & 0x7FF) - 1023;
        double man = ldexp(s, -es);
        float ll2 = lg2((float)man) + (float)(es + etot);
        ll_out[b] = ll2 * LN2;
    }
}

__global__ void finalize(const float* __restrict__ ll, float* __restrict__ out) {
    if (threadIdx.x == 0 && blockIdx.x == 0) {
        float s = 0.0f;
        #pragma unroll
        for (int b = 0; b < Bn; ++b) s += ll[b];
        out[0] = -s / (float)Bn;
    }
}

extern "C" void kernel_launch(void* const* d_in, const int* in_sizes, int n_in,
                              void* d_out, int out_size, void* d_ws, size_t ws_size,
                              hipStream_t stream) {
    const float* hs    = (const float*)d_in[0];
    const int*   hlens = (const int*)d_in[1];
    const int*   ys    = (const int*)d_in[2];
    const int*   ylens = (const int*)d_in[3];
    const float* W     = (const float*)d_in[4];
    const float* bias  = (const float*)d_in[5];
    float* out = (float*)d_out;

    char* ws = (char*)d_ws;
    unsigned short* hs_b = (unsigned short*)(ws);                       // 4,194,304 B
    unsigned short* w_b  = (unsigned short*)(ws + 4194304);             // 2,228,224 B
    unsigned short* wg_b = (unsigned short*)(ws + 6422528);             // 1,048,576 B
    float* glg2  = (float*)(ws + 7471104);                              // 2,621,440 B
    float* sep   = (float*)(ws + 10092544);                             // 1,114,112 B
    float* gbias = (float*)(ws + 11206656);                             //     8,192 B
    float* lse2  = (float*)(ws + 11214848);                             //    32,768 B
    float* ll    = (float*)(ws + 11247616);                             //        64 B

    conv<<<1024, 256, 0, stream>>>(hs, W, bias, ys, hs_b, w_b, wg_b, gbias);
    gemm_se<<<dim3(64, NCB + 1), 256, 0, stream>>>(hs_b, w_b, wg_b, bias, gbias, sep, glg2);
    lse_red<<<Mtot / 256, 256, 0, stream>>>(sep, lse2);
    ctc_fwd<<<Bn, 256, 0, stream>>>(glg2, lse2, ys, hlens, ylens, ll);
    finalize<<<1, 64, 0, stream>>>(ll, out);
}